// Round 11
// baseline (5217.241 us; speedup 1.0000x reference)
//
#include <hip/hip_runtime.h>
#include <hip/hip_bf16.h>

#define HID 1024
#define NBATCH 16
#define LSEQ 2048
#define OBSD 128
#define ACTD 16
#define INSZ 144
#define NBLK 64

typedef __bf16 bf16x8 __attribute__((ext_vector_type(8)));
typedef float f32x4 __attribute__((ext_vector_type(4)));
typedef unsigned int u32x4 __attribute__((ext_vector_type(4)));
typedef unsigned long long ull;

// ---------------- obs_target copy ----------------
__global__ __launch_bounds__(256) void k_copy_target(const float* __restrict__ obs,
                                                     float* __restrict__ tgt) {
    long long i = (long long)blockIdx.x * blockDim.x + threadIdx.x; // float4 idx
    const long long per_n = (long long)LSEQ * OBSD / 4;             // 65536
    if (i >= (long long)NBATCH * per_n) return;
    int n = (int)(i / per_n);
    long long r = i - (long long)n * per_n;
    const float4* src = (const float4*)obs;
    float4* dst = (float4*)tgt;
    dst[i] = src[(long long)n * (((LSEQ + 1) * OBSD) / 4) + (OBSD / 4) + r];
}

// ---------------- xproj: xp[l][n][d] -> written into ht[n][l][d] ----------------
__global__ __launch_bounds__(256) void k_xproj(const float* __restrict__ obs,
                                               const float* __restrict__ act,
                                               const float* __restrict__ W_ih,
                                               const float* __restrict__ bias,
                                               const float* __restrict__ noise,
                                               float* __restrict__ ht) {
    __shared__ float xs[NBATCH][INSZ];
    const int l = blockIdx.x;
    const int t = threadIdx.x;

    for (int i = t; i < NBATCH * INSZ; i += 256) {
        int n = i / INSZ, c = i % INSZ;
        float v = (c < OBSD) ? obs[((long long)n * (LSEQ + 1) + l) * OBSD + c]
                             : act[((long long)n * LSEQ + l) * ACTD + (c - OBSD)];
        xs[n][c] = v;
    }
    __syncthreads();

    const int d0 = t * 4;
    float4 bi = *(const float4*)(bias + d0);
    float4 no = *(const float4*)(noise + (long long)l * HID + d0);
    float acc[NBATCH][4];
#pragma unroll
    for (int nn = 0; nn < NBATCH; ++nn) {
        acc[nn][0] = bi.x + no.x; acc[nn][1] = bi.y + no.y;
        acc[nn][2] = bi.z + no.z; acc[nn][3] = bi.w + no.w;
    }
    for (int k = 0; k < INSZ; k += 4) {
        float4 w[4];
#pragma unroll
        for (int i = 0; i < 4; ++i)
            w[i] = *(const float4*)(W_ih + (long long)(d0 + i) * INSZ + k);
#pragma unroll
        for (int nn = 0; nn < NBATCH; ++nn) {
            float4 xv = *(const float4*)&xs[nn][k];
#pragma unroll
            for (int i = 0; i < 4; ++i)
                acc[nn][i] += xv.x * w[i].x + xv.y * w[i].y + xv.z * w[i].z + xv.w * w[i].w;
        }
    }
#pragma unroll
    for (int nn = 0; nn < NBATCH; ++nn) {
        float4 v = make_float4(acc[nn][0], acc[nn][1], acc[nn][2], acc[nn][3]);
        *(float4*)(ht + ((long long)nn * LSEQ + l) * HID + d0) = v;
    }
}

// ---------------- persistent scan ----------------
// 64 blocks x 64 threads. Block b owns output rows [16b,16b+16).
// ROUND-2 PROVEN GATED PROTOCOL (3/3 passes; flag-free retired at 0/3):
//   producer: 8B relaxed atomic data stores (step tag ((l>>1)&1)^1 in the
//             sign bit of halfword 0; h>=0 after ReLU so signs are free),
//             then lane 0 stores flags[b*32] = l+1 (padded 128B line).
//   consumer: GATE on flags[p] >= l for all p (monotonic-cached), then the
//             tag-validated L2-bypass (sc0 sc1) sweep.
// Staged fast path (acceptance predicate UNCHANGED):
//   * after a pre-drain vmcnt(0), issue all 32 loads, then per 4-quad group
//     {s_waitcnt vmcnt(28-4g); sched_barrier(0); validate; clear; MFMA} --
//     compute overlaps the load-return tail. If any group was stale (same
//     __all(bad) predicate), accumulators are discarded and the original
//     full sweep+MFMA loop runs as fallback.
//   * tag clear via AND 0xFFFF7FFF (true data is >=0, so bit15 is tag-only):
//     correct for BOTH tag values, no conditional, no wasted XORs at te=0.
// Asm outputs are early-clobber ("=&v") so the address pair never aliases a
// load destination.
__global__ __launch_bounds__(64, 1) void k_scan(const float* __restrict__ W_hh,
                                                float* __restrict__ ht,
                                                unsigned char* __restrict__ ws) {
    const int b = blockIdx.x;
    const int lane = threadIdx.x;
    const int n = lane & 15;
    const int quad = lane >> 4;
    const int jA = 16 * b + n;         // A-operand row of W
    const int jq = 16 * b + quad * 4;  // D rows base

    ull* hx[2] = { (ull*)ws, (ull*)(ws + 32 * 1024) };
    int* flags = (int*)(ws + 64 * 1024);   // stride 32 ints = 128B per block
    const unsigned int CM = 0xFFFF7FFFu;   // clear mask: drop bit15 (tag slot)

    // W_hh A-fragments in registers (bf16), 32 k-tiles
    bf16x8 wf[32];
#pragma unroll
    for (int t = 0; t < 32; ++t) {
        const float* p = W_hh + (long long)jA * HID + t * 32 + quad * 8;
        bf16x8 v;
#pragma unroll
        for (int e = 0; e < 8; ++e) v[e] = (__bf16)p[e];
        wf[t] = v;
    }
    // exact-diagonal fp32 correction terms
    float wdg[4], wdgb[4];
#pragma unroll
    for (int r = 0; r < 4; ++r) {
        float w = W_hh[(long long)(jq + r) * HID + (jq + r)];
        wdg[r] = w;
        wdgb[r] = (float)(__bf16)w;
    }

    const int myslot = b * 64 + n * 4 + quad;                 // producer ull slot
    const int cbase = 64 * (quad >> 1) + n * 4 + 2 * (quad & 1); // consumer base

    f32x4 hprev;
    float hbprev[4];
    // ---- step 0: h0 = relu(xp0), publish (tag 1, buf 0) ----
    {
        f32x4 xp = *(const f32x4*)(ht + ((long long)n * LSEQ + 0) * HID + jq);
        f32x4 h;
#pragma unroll
        for (int r = 0; r < 4; ++r) h[r] = fmaxf(xp[r], 0.f);
        ull q0 = 0;
#pragma unroll
        for (int r = 0; r < 4; ++r) {
            __bf16 x = (__bf16)h[r];
            hbprev[r] = (float)x;
            q0 |= (ull)__builtin_bit_cast(unsigned short, x) << (16 * r);
        }
        q0 |= (ull)1 << 15;  // tag for l=0 is 1
        __hip_atomic_store(&hx[0][myslot], q0, __ATOMIC_RELAXED, __HIP_MEMORY_SCOPE_AGENT);
        if (lane == 0)
            __hip_atomic_store(&flags[b * 32], 1, __ATOMIC_RELAXED, __HIP_MEMORY_SCOPE_AGENT);
        *(f32x4*)(ht + ((long long)n * LSEQ + 0) * HID + jq) = h;
        hprev = h;
    }

    int fvc = 0;  // monotonic flag cache

    // ---- steps 1..L-1 ----
    for (int l = 1; l < LSEQ; ++l) {
        f32x4 xp = *(const f32x4*)(ht + ((long long)n * LSEQ + l) * HID + jq);

        // ordering gate: one padded flag line per producer; skip if cached
        if (!__all(fvc >= l)) {
            do {
                fvc = __hip_atomic_load(&flags[lane * 32], __ATOMIC_RELAXED, __HIP_MEMORY_SCOPE_AGENT);
            } while (!__all(fvc >= l));
        }

        const ull* hb = hx[(l - 1) & 1];
        const unsigned int te = (unsigned int)((((l - 1) >> 1) & 1) ^ 1) << 15; // expected tag

        f32x4 a0 = xp;
        f32x4 a1 = {0.f, 0.f, 0.f, 0.f};
        f32x4 a2 = {0.f, 0.f, 0.f, 0.f};
        f32x4 a3 = {0.f, 0.f, 0.f, 0.f};

        u32x4 q[32];
        // ---- staged fast path ----
        // pre-drain: ensure only sweep loads are outstanding (covers the
        // gate-skip case where xp load + publish stores are still in flight)
        asm volatile("s_waitcnt vmcnt(0)" ::: "memory");
#pragma unroll
        for (int g = 0; g < 8; ++g) {
            const ull* p = hb + 512 * g + cbase;
            asm volatile(
                "global_load_dwordx4 %0, %4, off sc0 sc1\n\t"
                "global_load_dwordx4 %1, %4, off offset:1024 sc0 sc1\n\t"
                "global_load_dwordx4 %2, %4, off offset:2048 sc0 sc1\n\t"
                "global_load_dwordx4 %3, %4, off offset:3072 sc0 sc1"
                : "=&v"(q[4 * g]), "=&v"(q[4 * g + 1]),
                  "=&v"(q[4 * g + 2]), "=&v"(q[4 * g + 3])
                : "v"(p));
        }
        unsigned int bad = 0;
#pragma unroll
        for (int g = 0; g < 8; ++g) {
            switch (g) {  // wait for this group's 4 loads (in-order vmcnt)
                case 0: asm volatile("s_waitcnt vmcnt(28)" ::: "memory"); break;
                case 1: asm volatile("s_waitcnt vmcnt(24)" ::: "memory"); break;
                case 2: asm volatile("s_waitcnt vmcnt(20)" ::: "memory"); break;
                case 3: asm volatile("s_waitcnt vmcnt(16)" ::: "memory"); break;
                case 4: asm volatile("s_waitcnt vmcnt(12)" ::: "memory"); break;
                case 5: asm volatile("s_waitcnt vmcnt(8)" ::: "memory"); break;
                case 6: asm volatile("s_waitcnt vmcnt(4)" ::: "memory"); break;
                case 7: asm volatile("s_waitcnt vmcnt(0)" ::: "memory"); break;
            }
            __builtin_amdgcn_sched_barrier(0);
            const int t = 4 * g;
            // validate (before clear)
            bad |= (q[t].x ^ te) | (q[t].z ^ te);
            bad |= (q[t + 1].x ^ te) | (q[t + 1].z ^ te);
            bad |= (q[t + 2].x ^ te) | (q[t + 2].z ^ te);
            bad |= (q[t + 3].x ^ te) | (q[t + 3].z ^ te);
            // clear tag slots (bit15 of each quad's low dword)
            q[t].x &= CM;     q[t].z &= CM;
            q[t + 1].x &= CM; q[t + 1].z &= CM;
            q[t + 2].x &= CM; q[t + 2].z &= CM;
            q[t + 3].x &= CM; q[t + 3].z &= CM;
            union { u32x4 u; bf16x8 v; } c0, c1, c2, c3;
            c0.u = q[t]; c1.u = q[t + 1]; c2.u = q[t + 2]; c3.u = q[t + 3];
            a0 = __builtin_amdgcn_mfma_f32_16x16x32_bf16(wf[t], c0.v, a0, 0, 0, 0);
            a1 = __builtin_amdgcn_mfma_f32_16x16x32_bf16(wf[t + 1], c1.v, a1, 0, 0, 0);
            a2 = __builtin_amdgcn_mfma_f32_16x16x32_bf16(wf[t + 2], c2.v, a2, 0, 0, 0);
            a3 = __builtin_amdgcn_mfma_f32_16x16x32_bf16(wf[t + 3], c3.v, a3, 0, 0, 0);
        }

        // ---- fallback (rare post-gate): full sweep until valid, recompute ----
        if (!__all((bad & 0x8000u) == 0u)) {
            for (;;) {
#pragma unroll
                for (int g = 0; g < 8; ++g) {
                    const ull* p = hb + 512 * g + cbase;
                    asm volatile(
                        "global_load_dwordx4 %0, %4, off sc0 sc1\n\t"
                        "global_load_dwordx4 %1, %4, off offset:1024 sc0 sc1\n\t"
                        "global_load_dwordx4 %2, %4, off offset:2048 sc0 sc1\n\t"
                        "global_load_dwordx4 %3, %4, off offset:3072 sc0 sc1"
                        : "=&v"(q[4 * g]), "=&v"(q[4 * g + 1]),
                          "=&v"(q[4 * g + 2]), "=&v"(q[4 * g + 3])
                        : "v"(p));
                }
                asm volatile("s_waitcnt vmcnt(0)" ::: "memory");
                __builtin_amdgcn_sched_barrier(0);
                unsigned int bd = 0;
#pragma unroll
                for (int t = 0; t < 32; ++t)
                    bd |= (q[t].x ^ te) | (q[t].z ^ te);
                if (__all((bd & 0x8000u) == 0u)) break;
            }
#pragma unroll
            for (int t = 0; t < 32; ++t) { q[t].x &= CM; q[t].z &= CM; }
            a0 = xp;
            a1 = f32x4{0.f, 0.f, 0.f, 0.f};
            a2 = f32x4{0.f, 0.f, 0.f, 0.f};
            a3 = f32x4{0.f, 0.f, 0.f, 0.f};
#pragma unroll
            for (int t = 0; t < 32; t += 4) {
                union { u32x4 u; bf16x8 v; } c0, c1, c2, c3;
                c0.u = q[t]; c1.u = q[t + 1]; c2.u = q[t + 2]; c3.u = q[t + 3];
                a0 = __builtin_amdgcn_mfma_f32_16x16x32_bf16(wf[t], c0.v, a0, 0, 0, 0);
                a1 = __builtin_amdgcn_mfma_f32_16x16x32_bf16(wf[t + 1], c1.v, a1, 0, 0, 0);
                a2 = __builtin_amdgcn_mfma_f32_16x16x32_bf16(wf[t + 2], c2.v, a2, 0, 0, 0);
                a3 = __builtin_amdgcn_mfma_f32_16x16x32_bf16(wf[t + 3], c3.v, a3, 0, 0, 0);
            }
        }

#pragma unroll
        for (int r = 0; r < 4; ++r) {
            float v = (a0[r] + a1[r]) + (a2[r] + a3[r]);
            v += wdg[r] * hprev[r] - wdgb[r] * hbprev[r]; // exact fp32 diagonal
            hprev[r] = fmaxf(v, 0.f);
        }

        // publish step l: buf l&1, tag (((l>>1)&1)^1) in sign of halfword 0
        const ull tw = (ull)((((l >> 1) & 1) ^ 1)) << 15;
        ull qo = 0;
#pragma unroll
        for (int r = 0; r < 4; ++r) {
            __bf16 x = (__bf16)hprev[r];
            hbprev[r] = (float)x;
            qo |= (ull)__builtin_bit_cast(unsigned short, x) << (16 * r);
        }
        qo |= tw;
        __hip_atomic_store(&hx[l & 1][myslot], qo, __ATOMIC_RELAXED, __HIP_MEMORY_SCOPE_AGENT);
        if (lane == 0)
            __hip_atomic_store(&flags[b * 32], l + 1, __ATOMIC_RELAXED, __HIP_MEMORY_SCOPE_AGENT);
        *(f32x4*)(ht + ((long long)n * LSEQ + l) * HID + jq) = hprev;
    }
}

// ---------------- y = sigmoid(h @ W_out^T) ----------------
__global__ __launch_bounds__(256) void k_yout(const float* __restrict__ ht,
                                              const float* __restrict__ W_out,
                                              float* __restrict__ y) {
    __shared__ float hs[64 * 66];
    __shared__ float wt[128 * 66];
    const int t = threadIdx.x;
    const long long R0 = (long long)blockIdx.x * 64;
    const int rg = t >> 4;
    const int og = t & 15;

    float acc[4][8];
#pragma unroll
    for (int r = 0; r < 4; ++r)
#pragma unroll
        for (int o = 0; o < 8; ++o) acc[r][o] = 0.f;

    for (int kc = 0; kc < HID; kc += 64) {
        __syncthreads();
#pragma unroll
        for (int i = 0; i < 4; ++i) {
            int idx = t + i * 256;
            int r = idx >> 4, c = (idx & 15) * 4;
            float4 v = *(const float4*)(ht + (R0 + r) * HID + kc + c);
            *(float2*)&hs[r * 66 + c] = make_float2(v.x, v.y);
            *(float2*)&hs[r * 66 + c + 2] = make_float2(v.z, v.w);
        }
#pragma unroll
        for (int i = 0; i < 8; ++i) {
            int idx = t + i * 256;
            int o = idx >> 4, c = (idx & 15) * 4;
            float4 v = *(const float4*)(W_out + (long long)o * HID + kc + c);
            *(float2*)&wt[o * 66 + c] = make_float2(v.x, v.y);
            *(float2*)&wt[o * 66 + c + 2] = make_float2(v.z, v.w);
        }
        __syncthreads();
#pragma unroll
        for (int kk = 0; kk < 64; kk += 2) {
            float2 hv[4], wv[8];
#pragma unroll
            for (int r = 0; r < 4; ++r) hv[r] = *(const float2*)&hs[(rg * 4 + r) * 66 + kk];
#pragma unroll
            for (int o = 0; o < 8; ++o) wv[o] = *(const float2*)&wt[(og * 8 + o) * 66 + kk];
#pragma unroll
            for (int r = 0; r < 4; ++r)
#pragma unroll
                for (int o = 0; o < 8; ++o)
                    acc[r][o] += hv[r].x * wv[o].x + hv[r].y * wv[o].y;
        }
    }
#pragma unroll
    for (int r = 0; r < 4; ++r) {
        long long R = R0 + rg * 4 + r;
        float out[8];
#pragma unroll
        for (int o = 0; o < 8; ++o) out[o] = 1.f / (1.f + __expf(-acc[r][o]));
        *(float4*)(y + R * OBSD + og * 8) = make_float4(out[0], out[1], out[2], out[3]);
        *(float4*)(y + R * OBSD + og * 8 + 4) = make_float4(out[4], out[5], out[6], out[7]);
    }
}

extern "C" void kernel_launch(void* const* d_in, const int* in_sizes, int n_in,
                              void* d_out, int out_size, void* d_ws, size_t ws_size,
                              hipStream_t stream) {
    const float* obs = (const float*)d_in[0];
    const float* act = (const float*)d_in[1];
    const float* W_ih = (const float*)d_in[2];
    const float* W_hh = (const float*)d_in[3];
    const float* bias = (const float*)d_in[4];
    const float* W_out = (const float*)d_in[5];
    const float* noise = (const float*)d_in[6];

    float* y = (float*)d_out;                                   // 16*2048*128
    float* ht = y + (long long)NBATCH * LSEQ * OBSD;            // 16*2048*1024
    float* tgt = ht + (long long)NBATCH * LSEQ * HID;           // 16*2048*128
    unsigned char* ws = (unsigned char*)d_ws;

    k_copy_target<<<dim3(4096), dim3(256), 0, stream>>>(obs, tgt);
    k_xproj<<<dim3(LSEQ), dim3(256), 0, stream>>>(obs, act, W_ih, bias, noise, ht);
    k_scan<<<dim3(NBLK), dim3(64), 0, stream>>>(W_hh, ht, ws);
    k_yout<<<dim3(512), dim3(256), 0, stream>>>(ht, W_out, y);
}

// Round 12
// 4994.819 us; speedup vs baseline: 1.0445x; 1.0445x over previous
//
#include <hip/hip_runtime.h>
#include <hip/hip_bf16.h>

#define HID 1024
#define NBATCH 16
#define LSEQ 2048
#define OBSD 128
#define ACTD 16
#define INSZ 144
#define NBLK 64

typedef __bf16 bf16x8 __attribute__((ext_vector_type(8)));
typedef float f32x4 __attribute__((ext_vector_type(4)));
typedef unsigned int u32x4 __attribute__((ext_vector_type(4)));
typedef unsigned long long ull;

// ---------------- xproj + obs_target copy (fused) ----------------
// Block l: (1) tgt[:, l, :] = obs[:, l+1, :]; (2) xp[l][n][d] -> ht[n][l][d].
__global__ __launch_bounds__(256) void k_xproj(const float* __restrict__ obs,
                                               const float* __restrict__ act,
                                               const float* __restrict__ W_ih,
                                               const float* __restrict__ bias,
                                               const float* __restrict__ noise,
                                               float* __restrict__ ht,
                                               float* __restrict__ tgt) {
    __shared__ float xs[NBATCH][INSZ];
    const int l = blockIdx.x;
    const int t = threadIdx.x;

    // fused obs_target copy: 16 n x 32 float4 = 512 float4, 2 per thread
#pragma unroll
    for (int i = 0; i < 2; ++i) {
        int idx = t + i * 256;     // 0..511
        int n = idx >> 5;          // 32 float4 per batch row
        int c4 = idx & 31;
        float4 v = *(const float4*)(obs + ((long long)n * (LSEQ + 1) + (l + 1)) * OBSD + c4 * 4);
        *(float4*)(tgt + ((long long)n * LSEQ + l) * OBSD + c4 * 4) = v;
    }

    for (int i = t; i < NBATCH * INSZ; i += 256) {
        int n = i / INSZ, c = i % INSZ;
        float v = (c < OBSD) ? obs[((long long)n * (LSEQ + 1) + l) * OBSD + c]
                             : act[((long long)n * LSEQ + l) * ACTD + (c - OBSD)];
        xs[n][c] = v;
    }
    __syncthreads();

    const int d0 = t * 4;
    float4 bi = *(const float4*)(bias + d0);
    float4 no = *(const float4*)(noise + (long long)l * HID + d0);
    float acc[NBATCH][4];
#pragma unroll
    for (int nn = 0; nn < NBATCH; ++nn) {
        acc[nn][0] = bi.x + no.x; acc[nn][1] = bi.y + no.y;
        acc[nn][2] = bi.z + no.z; acc[nn][3] = bi.w + no.w;
    }
    for (int k = 0; k < INSZ; k += 4) {
        float4 w[4];
#pragma unroll
        for (int i = 0; i < 4; ++i)
            w[i] = *(const float4*)(W_ih + (long long)(d0 + i) * INSZ + k);
#pragma unroll
        for (int nn = 0; nn < NBATCH; ++nn) {
            float4 xv = *(const float4*)&xs[nn][k];
#pragma unroll
            for (int i = 0; i < 4; ++i)
                acc[nn][i] += xv.x * w[i].x + xv.y * w[i].y + xv.z * w[i].z + xv.w * w[i].w;
        }
    }
#pragma unroll
    for (int nn = 0; nn < NBATCH; ++nn) {
        float4 v = make_float4(acc[nn][0], acc[nn][1], acc[nn][2], acc[nn][3]);
        *(float4*)(ht + ((long long)nn * LSEQ + l) * HID + d0) = v;
    }
}

// ---------------- persistent scan (BYTE-IDENTICAL to round-11 PASS) ----------------
// 64 blocks x 64 threads. Block b owns output rows [16b,16b+16).
// ROUND-2 PROVEN GATED PROTOCOL (4/4 passes; flag-free retired at 0/3):
//   producer: 8B relaxed atomic data stores (step tag ((l>>1)&1)^1 in the
//             sign bit of halfword 0; h>=0 after ReLU so signs are free),
//             then lane 0 stores flags[b*32] = l+1 (padded 128B line).
//   consumer: GATE on flags[p] >= l for all p (monotonic-cached), then the
//             tag-validated L2-bypass (sc0 sc1) sweep.
// Staged fast path: after a pre-drain vmcnt(0), issue all 32 loads, then per
// 4-quad group {s_waitcnt vmcnt(28-4g); sched_barrier(0); validate; clear;
// MFMA}. On stale tags: gated full-sweep fallback.
__global__ __launch_bounds__(64, 1) void k_scan(const float* __restrict__ W_hh,
                                                float* __restrict__ ht,
                                                unsigned char* __restrict__ ws) {
    const int b = blockIdx.x;
    const int lane = threadIdx.x;
    const int n = lane & 15;
    const int quad = lane >> 4;
    const int jA = 16 * b + n;         // A-operand row of W
    const int jq = 16 * b + quad * 4;  // D rows base

    ull* hx[2] = { (ull*)ws, (ull*)(ws + 32 * 1024) };
    int* flags = (int*)(ws + 64 * 1024);   // stride 32 ints = 128B per block
    const unsigned int CM = 0xFFFF7FFFu;   // clear mask: drop bit15 (tag slot)

    // W_hh A-fragments in registers (bf16), 32 k-tiles
    bf16x8 wf[32];
#pragma unroll
    for (int t = 0; t < 32; ++t) {
        const float* p = W_hh + (long long)jA * HID + t * 32 + quad * 8;
        bf16x8 v;
#pragma unroll
        for (int e = 0; e < 8; ++e) v[e] = (__bf16)p[e];
        wf[t] = v;
    }
    // exact-diagonal fp32 correction terms
    float wdg[4], wdgb[4];
#pragma unroll
    for (int r = 0; r < 4; ++r) {
        float w = W_hh[(long long)(jq + r) * HID + (jq + r)];
        wdg[r] = w;
        wdgb[r] = (float)(__bf16)w;
    }

    const int myslot = b * 64 + n * 4 + quad;                 // producer ull slot
    const int cbase = 64 * (quad >> 1) + n * 4 + 2 * (quad & 1); // consumer base

    f32x4 hprev;
    float hbprev[4];
    // ---- step 0: h0 = relu(xp0), publish (tag 1, buf 0) ----
    {
        f32x4 xp = *(const f32x4*)(ht + ((long long)n * LSEQ + 0) * HID + jq);
        f32x4 h;
#pragma unroll
        for (int r = 0; r < 4; ++r) h[r] = fmaxf(xp[r], 0.f);
        ull q0 = 0;
#pragma unroll
        for (int r = 0; r < 4; ++r) {
            __bf16 x = (__bf16)h[r];
            hbprev[r] = (float)x;
            q0 |= (ull)__builtin_bit_cast(unsigned short, x) << (16 * r);
        }
        q0 |= (ull)1 << 15;  // tag for l=0 is 1
        __hip_atomic_store(&hx[0][myslot], q0, __ATOMIC_RELAXED, __HIP_MEMORY_SCOPE_AGENT);
        if (lane == 0)
            __hip_atomic_store(&flags[b * 32], 1, __ATOMIC_RELAXED, __HIP_MEMORY_SCOPE_AGENT);
        *(f32x4*)(ht + ((long long)n * LSEQ + 0) * HID + jq) = h;
        hprev = h;
    }

    int fvc = 0;  // monotonic flag cache

    // ---- steps 1..L-1 ----
    for (int l = 1; l < LSEQ; ++l) {
        f32x4 xp = *(const f32x4*)(ht + ((long long)n * LSEQ + l) * HID + jq);

        // ordering gate: one padded flag line per producer; skip if cached
        if (!__all(fvc >= l)) {
            do {
                fvc = __hip_atomic_load(&flags[lane * 32], __ATOMIC_RELAXED, __HIP_MEMORY_SCOPE_AGENT);
            } while (!__all(fvc >= l));
        }

        const ull* hb = hx[(l - 1) & 1];
        const unsigned int te = (unsigned int)((((l - 1) >> 1) & 1) ^ 1) << 15; // expected tag

        f32x4 a0 = xp;
        f32x4 a1 = {0.f, 0.f, 0.f, 0.f};
        f32x4 a2 = {0.f, 0.f, 0.f, 0.f};
        f32x4 a3 = {0.f, 0.f, 0.f, 0.f};

        u32x4 q[32];
        // ---- staged fast path ----
        asm volatile("s_waitcnt vmcnt(0)" ::: "memory");
#pragma unroll
        for (int g = 0; g < 8; ++g) {
            const ull* p = hb + 512 * g + cbase;
            asm volatile(
                "global_load_dwordx4 %0, %4, off sc0 sc1\n\t"
                "global_load_dwordx4 %1, %4, off offset:1024 sc0 sc1\n\t"
                "global_load_dwordx4 %2, %4, off offset:2048 sc0 sc1\n\t"
                "global_load_dwordx4 %3, %4, off offset:3072 sc0 sc1"
                : "=&v"(q[4 * g]), "=&v"(q[4 * g + 1]),
                  "=&v"(q[4 * g + 2]), "=&v"(q[4 * g + 3])
                : "v"(p));
        }
        unsigned int bad = 0;
#pragma unroll
        for (int g = 0; g < 8; ++g) {
            switch (g) {  // wait for this group's 4 loads (in-order vmcnt)
                case 0: asm volatile("s_waitcnt vmcnt(28)" ::: "memory"); break;
                case 1: asm volatile("s_waitcnt vmcnt(24)" ::: "memory"); break;
                case 2: asm volatile("s_waitcnt vmcnt(20)" ::: "memory"); break;
                case 3: asm volatile("s_waitcnt vmcnt(16)" ::: "memory"); break;
                case 4: asm volatile("s_waitcnt vmcnt(12)" ::: "memory"); break;
                case 5: asm volatile("s_waitcnt vmcnt(8)" ::: "memory"); break;
                case 6: asm volatile("s_waitcnt vmcnt(4)" ::: "memory"); break;
                case 7: asm volatile("s_waitcnt vmcnt(0)" ::: "memory"); break;
            }
            __builtin_amdgcn_sched_barrier(0);
            const int t = 4 * g;
            bad |= (q[t].x ^ te) | (q[t].z ^ te);
            bad |= (q[t + 1].x ^ te) | (q[t + 1].z ^ te);
            bad |= (q[t + 2].x ^ te) | (q[t + 2].z ^ te);
            bad |= (q[t + 3].x ^ te) | (q[t + 3].z ^ te);
            q[t].x &= CM;     q[t].z &= CM;
            q[t + 1].x &= CM; q[t + 1].z &= CM;
            q[t + 2].x &= CM; q[t + 2].z &= CM;
            q[t + 3].x &= CM; q[t + 3].z &= CM;
            union { u32x4 u; bf16x8 v; } c0, c1, c2, c3;
            c0.u = q[t]; c1.u = q[t + 1]; c2.u = q[t + 2]; c3.u = q[t + 3];
            a0 = __builtin_amdgcn_mfma_f32_16x16x32_bf16(wf[t], c0.v, a0, 0, 0, 0);
            a1 = __builtin_amdgcn_mfma_f32_16x16x32_bf16(wf[t + 1], c1.v, a1, 0, 0, 0);
            a2 = __builtin_amdgcn_mfma_f32_16x16x32_bf16(wf[t + 2], c2.v, a2, 0, 0, 0);
            a3 = __builtin_amdgcn_mfma_f32_16x16x32_bf16(wf[t + 3], c3.v, a3, 0, 0, 0);
        }

        // ---- fallback (rare post-gate): full sweep until valid, recompute ----
        if (!__all((bad & 0x8000u) == 0u)) {
            for (;;) {
#pragma unroll
                for (int g = 0; g < 8; ++g) {
                    const ull* p = hb + 512 * g + cbase;
                    asm volatile(
                        "global_load_dwordx4 %0, %4, off sc0 sc1\n\t"
                        "global_load_dwordx4 %1, %4, off offset:1024 sc0 sc1\n\t"
                        "global_load_dwordx4 %2, %4, off offset:2048 sc0 sc1\n\t"
                        "global_load_dwordx4 %3, %4, off offset:3072 sc0 sc1"
                        : "=&v"(q[4 * g]), "=&v"(q[4 * g + 1]),
                          "=&v"(q[4 * g + 2]), "=&v"(q[4 * g + 3])
                        : "v"(p));
                }
                asm volatile("s_waitcnt vmcnt(0)" ::: "memory");
                __builtin_amdgcn_sched_barrier(0);
                unsigned int bd = 0;
#pragma unroll
                for (int t = 0; t < 32; ++t)
                    bd |= (q[t].x ^ te) | (q[t].z ^ te);
                if (__all((bd & 0x8000u) == 0u)) break;
            }
#pragma unroll
            for (int t = 0; t < 32; ++t) { q[t].x &= CM; q[t].z &= CM; }
            a0 = xp;
            a1 = f32x4{0.f, 0.f, 0.f, 0.f};
            a2 = f32x4{0.f, 0.f, 0.f, 0.f};
            a3 = f32x4{0.f, 0.f, 0.f, 0.f};
#pragma unroll
            for (int t = 0; t < 32; t += 4) {
                union { u32x4 u; bf16x8 v; } c0, c1, c2, c3;
                c0.u = q[t]; c1.u = q[t + 1]; c2.u = q[t + 2]; c3.u = q[t + 3];
                a0 = __builtin_amdgcn_mfma_f32_16x16x32_bf16(wf[t], c0.v, a0, 0, 0, 0);
                a1 = __builtin_amdgcn_mfma_f32_16x16x32_bf16(wf[t + 1], c1.v, a1, 0, 0, 0);
                a2 = __builtin_amdgcn_mfma_f32_16x16x32_bf16(wf[t + 2], c2.v, a2, 0, 0, 0);
                a3 = __builtin_amdgcn_mfma_f32_16x16x32_bf16(wf[t + 3], c3.v, a3, 0, 0, 0);
            }
        }

#pragma unroll
        for (int r = 0; r < 4; ++r) {
            float v = (a0[r] + a1[r]) + (a2[r] + a3[r]);
            v += wdg[r] * hprev[r] - wdgb[r] * hbprev[r]; // exact fp32 diagonal
            hprev[r] = fmaxf(v, 0.f);
        }

        // publish step l: buf l&1, tag (((l>>1)&1)^1) in sign of halfword 0
        const ull tw = (ull)((((l >> 1) & 1) ^ 1)) << 15;
        ull qo = 0;
#pragma unroll
        for (int r = 0; r < 4; ++r) {
            __bf16 x = (__bf16)hprev[r];
            hbprev[r] = (float)x;
            qo |= (ull)__builtin_bit_cast(unsigned short, x) << (16 * r);
        }
        qo |= tw;
        __hip_atomic_store(&hx[l & 1][myslot], qo, __ATOMIC_RELAXED, __HIP_MEMORY_SCOPE_AGENT);
        if (lane == 0)
            __hip_atomic_store(&flags[b * 32], l + 1, __ATOMIC_RELAXED, __HIP_MEMORY_SCOPE_AGENT);
        *(f32x4*)(ht + ((long long)n * LSEQ + l) * HID + jq) = hprev;
    }
}

// ---------------- y = sigmoid(h @ W_out^T), bf16 MFMA ----------------
// 512 blocks x 256 threads (4 waves). Wave w owns 16 rows R0 = (bid*4+w)*16.
// MFMA 16x16x32 bf16: A = W_out (rows o), B = h (cols = R-rows).
// Fragment mapping (proven in k_scan): A lane&15 = A-row, quad*8 = k-offset;
// B lane&15 = col, quad*8 = k-offset; D col = lane&15 (R-row),
// row = quad*4+i (o within tile).
__global__ __launch_bounds__(256) void k_yout(const float* __restrict__ ht,
                                              const float* __restrict__ W_out,
                                              float* __restrict__ y) {
    const int wv = threadIdx.x >> 6;
    const int lane = threadIdx.x & 63;
    const int rr = lane & 15;
    const int quad = lane >> 4;
    const long long R0 = ((long long)blockIdx.x * 4 + wv) * 16;
    const float* hrow = ht + (R0 + rr) * HID;

    f32x4 acc[8];
#pragma unroll
    for (int ot = 0; ot < 8; ++ot) acc[ot] = f32x4{0.f, 0.f, 0.f, 0.f};

    for (int kt = 0; kt < 32; ++kt) {
        const int k0 = kt * 32 + quad * 8;
        bf16x8 bfr;
        {
            const float* hp = hrow + k0;
#pragma unroll
            for (int e = 0; e < 8; ++e) bfr[e] = (__bf16)hp[e];
        }
#pragma unroll
        for (int ot = 0; ot < 8; ++ot) {
            const float* wp = W_out + (long long)(ot * 16 + rr) * HID + k0;
            bf16x8 afr;
#pragma unroll
            for (int e = 0; e < 8; ++e) afr[e] = (__bf16)wp[e];
            acc[ot] = __builtin_amdgcn_mfma_f32_16x16x32_bf16(afr, bfr, acc[ot], 0, 0, 0);
        }
    }

#pragma unroll
    for (int ot = 0; ot < 8; ++ot) {
        float o4[4];
#pragma unroll
        for (int i = 0; i < 4; ++i) o4[i] = 1.f / (1.f + __expf(-acc[ot][i]));
        *(float4*)(y + (R0 + rr) * OBSD + ot * 16 + quad * 4) =
            make_float4(o4[0], o4[1], o4[2], o4[3]);
    }
}

extern "C" void kernel_launch(void* const* d_in, const int* in_sizes, int n_in,
                              void* d_out, int out_size, void* d_ws, size_t ws_size,
                              hipStream_t stream) {
    const float* obs = (const float*)d_in[0];
    const float* act = (const float*)d_in[1];
    const float* W_ih = (const float*)d_in[2];
    const float* W_hh = (const float*)d_in[3];
    const float* bias = (const float*)d_in[4];
    const float* W_out = (const float*)d_in[5];
    const float* noise = (const float*)d_in[6];

    float* y = (float*)d_out;                                   // 16*2048*128
    float* ht = y + (long long)NBATCH * LSEQ * OBSD;            // 16*2048*1024
    float* tgt = ht + (long long)NBATCH * LSEQ * HID;           // 16*2048*128
    unsigned char* ws = (unsigned char*)d_ws;

    k_xproj<<<dim3(LSEQ), dim3(256), 0, stream>>>(obs, act, W_ih, bias, noise, ht, tgt);
    k_scan<<<dim3(NBLK), dim3(64), 0, stream>>>(W_hh, ht, ws);
    k_yout<<<dim3(512), dim3(256), 0, stream>>>(ht, W_out, y);
}